// Round 1
// baseline (535.274 us; speedup 1.0000x reference)
//
#include <hip/hip_runtime.h>
#include <hip/hip_bf16.h>

#define NPER 68
#define EPER 544
#define FH   128
#define NC   8

// One block per graph. 256 threads = 4 waves.
// LDS ~79.7 KB -> 2 blocks/CU (8 waves/CU).
__launch_bounds__(256, 2)
__global__ void gnn_kernel(const float* __restrict__ x,
                           const int*   __restrict__ ei,
                           const float* __restrict__ s,
                           const float* __restrict__ Wroot1, const float* __restrict__ Wrel1, const float* __restrict__ b1,
                           const float* __restrict__ Wroot2, const float* __restrict__ Wrel2, const float* __restrict__ b2,
                           const float* __restrict__ Wroot3, const float* __restrict__ Wrel3, const float* __restrict__ b3,
                           const float* __restrict__ fcw, const float* __restrict__ fcb,
                           float* __restrict__ out, int nE)
{
    __shared__ float hbuf[NPER][FH];      // 34816 B
    __shared__ float abuf[NPER][FH];      // 34816 B
    __shared__ unsigned short edst_t[EPER]; // 1088 B
    __shared__ unsigned short esrc[EPER];   // 1088 B (CSR-ordered source list)
    __shared__ int   cnt[NPER];
    __shared__ int   coff[NPER + 1];
    __shared__ float xl[NPER][2];
    __shared__ float aggx[NPER][2];
    __shared__ float ssm[NPER][NC];       // also reused as reduction buffer
    __shared__ float xp[NC][FH];

    const int g     = blockIdx.x;
    const int tid   = threadIdx.x;
    const int gnode = g * NPER;
    const int gedge = g * EPER;

    const int* srcp = ei;
    const int* dstp = ei + nE;

    if (tid < NPER) cnt[tid] = 0;
    for (int i = tid; i < NPER * 2; i += 256)
        ((float*)xl)[i] = x[gnode * 2 + i];
    __syncthreads();

    // ---- build CSR over incoming edges (local ids) ----
    for (int e = tid; e < EPER; e += 256) {
        int gd = dstp[gedge + e] - gnode;
        edst_t[e] = (unsigned short)gd;
        atomicAdd(&cnt[gd], 1);
    }
    __syncthreads();
    if (tid == 0) {
        int acc = 0; coff[0] = 0;
        for (int i = 0; i < NPER; ++i) { acc += cnt[i]; coff[i + 1] = acc; }
    }
    __syncthreads();
    if (tid < NPER) cnt[tid] = coff[tid];   // cursors
    __syncthreads();
    for (int e = tid; e < EPER; e += 256) {
        int gd  = edst_t[e];
        int pos = atomicAdd(&cnt[gd], 1);
        esrc[pos] = (unsigned short)(srcp[gedge + e] - gnode);
    }
    __syncthreads();

    // ---- layer 1 (F_IN = 2) ----
    for (int i = tid; i < NPER; i += 256) {
        float s0 = 0.f, s1 = 0.f;
        for (int e = coff[i]; e < coff[i + 1]; ++e) {
            int si = esrc[e];
            s0 += xl[si][0]; s1 += xl[si][1];
        }
        aggx[i][0] = s0; aggx[i][1] = s1;
    }
    __syncthreads();
    for (int idx = tid; idx < NPER * FH; idx += 256) {
        int i = idx >> 7, f = idx & 127;
        float v = b1[f]
                + aggx[i][0] * Wrel1[f]      + aggx[i][1] * Wrel1[FH + f]
                + xl[i][0]   * Wroot1[f]     + xl[i][1]   * Wroot1[FH + f];
        hbuf[i][f] = v > 0.f ? v : 0.f;
    }
    __syncthreads();

    // ---- layers 2 and 3 ----
    const float* WlA[2] = {Wrel2, Wrel3};
    const float* WrA[2] = {Wroot2, Wroot3};
    const float* bA[2]  = {b2, b3};
    #pragma unroll
    for (int layer = 0; layer < 2; ++layer) {
        // neighbor aggregation: abuf[i][f] = sum_{src->i} hbuf[src][f]
        for (int idx = tid; idx < NPER * FH; idx += 256) {
            int i = idx >> 7, f = idx & 127;
            float sum = 0.f;
            int e0 = coff[i], e1 = coff[i + 1];
            for (int e = e0; e < e1; ++e) sum += hbuf[esrc[e]][f];
            abuf[i][f] = sum;
        }
        __syncthreads();

        // dense: h' = relu(abuf @ Wrel + hbuf @ Wroot + b)
        const float* __restrict__ Wl = WlA[layer];
        const float* __restrict__ Wr = WrA[layer];
        const float* __restrict__ bv = bA[layer];
        const int f0 = (tid & 63) * 2;
        const int rg = tid >> 6;          // 0..3, rows rg + 4*r
        float acc0[17], acc1[17];
        #pragma unroll
        for (int r = 0; r < 17; ++r) { acc0[r] = 0.f; acc1[r] = 0.f; }

        for (int k = 0; k < FH; k += 4) {
            float2 wl0 = *(const float2*)&Wl[(k + 0) * FH + f0];
            float2 wl1 = *(const float2*)&Wl[(k + 1) * FH + f0];
            float2 wl2 = *(const float2*)&Wl[(k + 2) * FH + f0];
            float2 wl3 = *(const float2*)&Wl[(k + 3) * FH + f0];
            float2 wr0 = *(const float2*)&Wr[(k + 0) * FH + f0];
            float2 wr1 = *(const float2*)&Wr[(k + 1) * FH + f0];
            float2 wr2 = *(const float2*)&Wr[(k + 2) * FH + f0];
            float2 wr3 = *(const float2*)&Wr[(k + 3) * FH + f0];
            #pragma unroll
            for (int r = 0; r < 17; ++r) {
                int i = rg + 4 * r;
                float4 av = *(const float4*)&abuf[i][k];
                float4 hv = *(const float4*)&hbuf[i][k];
                acc0[r] += av.x * wl0.x + av.y * wl1.x + av.z * wl2.x + av.w * wl3.x
                         + hv.x * wr0.x + hv.y * wr1.x + hv.z * wr2.x + hv.w * wr3.x;
                acc1[r] += av.x * wl0.y + av.y * wl1.y + av.z * wl2.y + av.w * wl3.y
                         + hv.x * wr0.y + hv.y * wr1.y + hv.z * wr2.y + hv.w * wr3.y;
            }
        }
        __syncthreads();   // all reads of hbuf done before overwrite
        const float bias0 = bv[f0], bias1 = bv[f0 + 1];
        #pragma unroll
        for (int r = 0; r < 17; ++r) {
            int i = rg + 4 * r;
            float v0 = acc0[r] + bias0; hbuf[i][f0]     = v0 > 0.f ? v0 : 0.f;
            float v1 = acc1[r] + bias1; hbuf[i][f0 + 1] = v1 > 0.f ? v1 : 0.f;
        }
        __syncthreads();
    }

    // ---- diff-pool: softmax(s) then xp[c][f] = sum_n ssm[n][c]*h[n][f] ----
    for (int i = tid; i < NPER; i += 256) {
        float v[NC]; float m = -1e30f;
        #pragma unroll
        for (int c = 0; c < NC; ++c) { v[c] = s[(gnode + i) * NC + c]; m = fmaxf(m, v[c]); }
        float sum = 0.f;
        #pragma unroll
        for (int c = 0; c < NC; ++c) { v[c] = __expf(v[c] - m); sum += v[c]; }
        float inv = 1.f / sum;
        #pragma unroll
        for (int c = 0; c < NC; ++c) ssm[i][c] = v[c] * inv;
    }
    __syncthreads();
    for (int idx = tid; idx < NC * FH; idx += 256) {
        int c = idx >> 7, f = idx & 127;
        float sum = 0.f;
        for (int n = 0; n < NPER; ++n) sum += ssm[n][c] * hbuf[n][f];
        xp[c][f] = sum;
    }
    __syncthreads();

    // ---- maxpool (1,8) + FC ----
    float partial = 0.f;
    if (tid < 128) {
        int c = tid >> 4, q = tid & 15;
        float m = xp[c][q * 8];
        #pragma unroll
        for (int j = 1; j < 8; ++j) m = fmaxf(m, xp[c][q * 8 + j]);
        partial = m * fcw[tid];
    }
    __syncthreads();                 // ssm no longer needed -> reuse as reduction buf
    float* red = &ssm[0][0];
    if (tid < 128) red[tid] = partial;
    __syncthreads();
    if (tid < 64) {
        float v = red[tid] + red[tid + 64];
        #pragma unroll
        for (int off = 32; off > 0; off >>= 1) v += __shfl_down(v, off, 64);
        if (tid == 0) out[g] = v + fcb[0];
    }
}

extern "C" void kernel_launch(void* const* d_in, const int* in_sizes, int n_in,
                              void* d_out, int out_size, void* d_ws, size_t ws_size,
                              hipStream_t stream) {
    const float* x      = (const float*)d_in[0];
    const int*   ei     = (const int*)d_in[1];
    // d_in[2] = adj: unused by the returned value
    const float* s      = (const float*)d_in[3];
    const float* Wroot1 = (const float*)d_in[4];
    const float* Wrel1  = (const float*)d_in[5];
    const float* b1     = (const float*)d_in[6];
    const float* Wroot2 = (const float*)d_in[7];
    const float* Wrel2  = (const float*)d_in[8];
    const float* b2     = (const float*)d_in[9];
    const float* Wroot3 = (const float*)d_in[10];
    const float* Wrel3  = (const float*)d_in[11];
    const float* b3     = (const float*)d_in[12];
    const float* fcw    = (const float*)d_in[13];
    const float* fcb    = (const float*)d_in[14];
    float* out = (float*)d_out;

    const int nE = in_sizes[1] / 2;           // 1,114,112
    const int B  = in_sizes[3] / (NPER * NC); // 2048

    gnn_kernel<<<B, 256, 0, stream>>>(x, ei, s,
                                      Wroot1, Wrel1, b1,
                                      Wroot2, Wrel2, b2,
                                      Wroot3, Wrel3, b3,
                                      fcw, fcb, out, nE);
}

// Round 2
// 207.721 us; speedup vs baseline: 2.5769x; 2.5769x over previous
//
#include <hip/hip_runtime.h>
#include <hip/hip_bf16.h>

#define NPER 68
#define ROWP 80
#define EPER 544
#define FH   128
#define NC   8

typedef short short8 __attribute__((ext_vector_type(8)));
typedef short short4v __attribute__((ext_vector_type(4)));
typedef float f32x4 __attribute__((ext_vector_type(4)));

__device__ __forceinline__ unsigned short f2bf(float f) {
    unsigned int u = __float_as_uint(f);
    return (unsigned short)((u + 0x7FFFu + ((u >> 16) & 1u)) >> 16);
}
__device__ __forceinline__ float bf2f(unsigned short h) {
    return __uint_as_float(((unsigned int)h) << 16);
}
// swizzled byte offset into hcat: row stride 512B, XOR bits 4..6 with row&7
__device__ __forceinline__ unsigned int swz(unsigned int row, unsigned int bytecol) {
    return row * 512u + (bytecol ^ ((row & 7u) << 4));
}

// Pack [Wrel;Wroot] (256x128 f32) into MFMA-B-fragment-ordered bf16:
// ws[(((L*8+t)*8+n)*64+l)*8+j] = Wcat[t*32+(l>>4)*8+j][n*16+(l&15)]
__global__ void pack_w(const float* __restrict__ Wrel2, const float* __restrict__ Wroot2,
                       const float* __restrict__ Wrel3, const float* __restrict__ Wroot3,
                       unsigned short* __restrict__ ws) {
    int o = blockIdx.x * 256 + threadIdx.x;      // < 65536
    int j = o & 7, l = (o >> 3) & 63, n = (o >> 9) & 7, t = (o >> 12) & 7, L = o >> 15;
    int k = t * 32 + ((l >> 4) << 3) + j;
    int f = n * 16 + (l & 15);
    const float* Wl = L ? Wrel3 : Wrel2;
    const float* Wr = L ? Wroot3 : Wroot2;
    float v = (k < FH) ? Wl[k * FH + f] : Wr[(k - FH) * FH + f];
    ws[o] = f2bf(v);
}

// One block per graph, 256 threads = 4 waves. LDS ~51KB -> 3 blocks/CU.
__launch_bounds__(256, 3)
__global__ void gnn_kernel(const float* __restrict__ x,
                           const int*   __restrict__ ei,
                           const float* __restrict__ s,
                           const float* __restrict__ Wroot1, const float* __restrict__ Wrel1, const float* __restrict__ b1,
                           const float* __restrict__ b2, const float* __restrict__ b3,
                           const unsigned short* __restrict__ wpack,
                           const float* __restrict__ fcw, const float* __restrict__ fcb,
                           float* __restrict__ out, int nE)
{
    // hcat[row][k]: k in [0,128) = agg part, [128,256) = h part. bf16, swizzled.
    __shared__ __align__(16) unsigned short hcat[ROWP * 256];   // 40960 B
    __shared__ unsigned short edst_t[EPER];                     // 1088 B
    __shared__ unsigned short esrc[EPER];                       // 1088 B
    __shared__ int   cnt[NPER];
    __shared__ int   coff[NPER + 1];
    __shared__ float xl[NPER][2];
    __shared__ float aggx[NPER][2];
    __shared__ float ssm[NPER][NC];                             // 2176 B (reused as red)
    __shared__ float xp[NC][FH];                                // 4096 B

    const int g     = blockIdx.x;
    const int tid   = threadIdx.x;
    const int lane  = tid & 63;
    const int wid   = tid >> 6;
    const int gnode = g * NPER;
    const int gedge = g * EPER;

    const int* srcp = ei;
    const int* dstp = ei + nE;

    if (tid < NPER) cnt[tid] = 0;
    for (int i = tid; i < NPER * 2; i += 256)
        ((float*)xl)[i] = x[gnode * 2 + i];
    // zero pad rows 68..79 (both halves); swizzle permutes within-row -> row memset ok
    for (int i = tid; i < (ROWP - NPER) * 128; i += 256)
        ((unsigned int*)(hcat + NPER * 256))[i] = 0u;
    __syncthreads();

    // ---- build CSR over incoming edges (local ids) ----
    for (int e = tid; e < EPER; e += 256) {
        int gd = dstp[gedge + e] - gnode;
        edst_t[e] = (unsigned short)gd;
        atomicAdd(&cnt[gd], 1);
    }
    __syncthreads();
    if (tid == 0) {
        int acc = 0; coff[0] = 0;
        for (int i = 0; i < NPER; ++i) { acc += cnt[i]; coff[i + 1] = acc; }
    }
    __syncthreads();
    if (tid < NPER) cnt[tid] = coff[tid];
    __syncthreads();
    for (int e = tid; e < EPER; e += 256) {
        int gd  = edst_t[e];
        int pos = atomicAdd(&cnt[gd], 1);
        esrc[pos] = (unsigned short)(srcp[gedge + e] - gnode);
    }
    __syncthreads();

    // ---- layer 1 (F_IN = 2), fp32 VALU ----
    for (int i = tid; i < NPER; i += 256) {
        float s0 = 0.f, s1 = 0.f;
        for (int e = coff[i]; e < coff[i + 1]; ++e) {
            int si = esrc[e];
            s0 += xl[si][0]; s1 += xl[si][1];
        }
        aggx[i][0] = s0; aggx[i][1] = s1;
    }
    __syncthreads();
    for (int idx = tid; idx < NPER * FH; idx += 256) {
        int i = idx >> 7, f = idx & 127;
        float v = b1[f]
                + aggx[i][0] * Wrel1[f]  + aggx[i][1] * Wrel1[FH + f]
                + xl[i][0]   * Wroot1[f] + xl[i][1]   * Wroot1[FH + f];
        v = v > 0.f ? v : 0.f;
        *(unsigned short*)((char*)hcat + swz(i, (128 + f) * 2)) = f2bf(v);
    }
    __syncthreads();

    // ---- layers 2 and 3: edge-agg (VALU) + fused MFMA GEMM ----
    #pragma unroll
    for (int L = 0; L < 2; ++L) {
        // aggregation: hcat[i][0..127] = sum_{src->i} hcat[src][128..255]
        for (int idx = tid; idx < NPER * 16; idx += 256) {
            int i = idx >> 4, fg = idx & 15;
            float acc[8];
            #pragma unroll
            for (int j = 0; j < 8; ++j) acc[j] = 0.f;
            int e0 = coff[i], e1 = coff[i + 1];
            for (int e = e0; e < e1; ++e) {
                int src = esrc[e];
                short8 hv = *(const short8*)((char*)hcat + swz(src, 256 + fg * 16));
                #pragma unroll
                for (int j = 0; j < 8; ++j) acc[j] += bf2f((unsigned short)hv[j]);
            }
            short8 r;
            #pragma unroll
            for (int j = 0; j < 8; ++j) r[j] = (short)f2bf(acc[j]);
            *(short8*)((char*)hcat + swz(i, fg * 16)) = r;
        }
        __syncthreads();

        // GEMM: D[80][128] = hcat[80][256] @ Wcat[256][128]; wave owns 2 col-tiles
        const unsigned short* wsL = wpack + (L << 15);
        f32x4 acc[5][2];
        #pragma unroll
        for (int m = 0; m < 5; ++m) { acc[m][0] = (f32x4)0.f; acc[m][1] = (f32x4)0.f; }
        const int arow = lane & 15, akoff = (lane >> 4) * 8;
        for (int t = 0; t < 8; ++t) {
            short8 bf0 = *(const short8*)(wsL + (((t * 8 + wid * 2 + 0) * 64 + lane) << 3));
            short8 bf1 = *(const short8*)(wsL + (((t * 8 + wid * 2 + 1) * 64 + lane) << 3));
            int k = t * 32 + akoff;
            #pragma unroll
            for (int m = 0; m < 5; ++m) {
                short8 a = *(const short8*)((char*)hcat + swz(m * 16 + arow, k * 2));
                acc[m][0] = __builtin_amdgcn_mfma_f32_16x16x32_bf16(a, bf0, acc[m][0], 0, 0, 0);
                acc[m][1] = __builtin_amdgcn_mfma_f32_16x16x32_bf16(a, bf1, acc[m][1], 0, 0, 0);
            }
        }
        __syncthreads();   // all A reads done before h-part overwrite

        const float* bv = L ? b3 : b2;
        #pragma unroll
        for (int c2 = 0; c2 < 2; ++c2) {
            int f = (wid * 2 + c2) * 16 + (lane & 15);
            float bias = bv[f];
            #pragma unroll
            for (int m = 0; m < 5; ++m) {
                #pragma unroll
                for (int i2 = 0; i2 < 4; ++i2) {
                    int row = m * 16 + (lane >> 4) * 4 + i2;
                    float v = acc[m][c2][i2] + bias;
                    v = v > 0.f ? v : 0.f;
                    *(unsigned short*)((char*)hcat + swz(row, (128 + f) * 2)) = f2bf(v);
                }
            }
        }
        __syncthreads();
    }

    // ---- diff-pool softmax ----
    for (int i = tid; i < NPER; i += 256) {
        float v[NC]; float m = -1e30f;
        #pragma unroll
        for (int c = 0; c < NC; ++c) { v[c] = s[(gnode + i) * NC + c]; m = fmaxf(m, v[c]); }
        float sum = 0.f;
        #pragma unroll
        for (int c = 0; c < NC; ++c) { v[c] = __expf(v[c] - m); sum += v[c]; }
        float inv = 1.f / sum;
        #pragma unroll
        for (int c = 0; c < NC; ++c) ssm[i][c] = v[c] * inv;
    }
    __syncthreads();

    // xp[c][f] = sum_n ssm[n][c] * h[n][f]; thread = (c, 4 features)
    {
        int c = tid >> 5, fq = tid & 31;
        float a4[4] = {0.f, 0.f, 0.f, 0.f};
        for (int n = 0; n < NPER; ++n) {
            float sc = ssm[n][c];
            short4v hv = *(const short4v*)((char*)hcat + swz(n, 256 + fq * 8));
            #pragma unroll
            for (int j = 0; j < 4; ++j) a4[j] += sc * bf2f((unsigned short)hv[j]);
        }
        #pragma unroll
        for (int j = 0; j < 4; ++j) xp[c][fq * 4 + j] = a4[j];
    }
    __syncthreads();

    // ---- maxpool (1,8) + FC ----
    float partial = 0.f;
    if (tid < 128) {
        int c = tid >> 4, q = tid & 15;
        float m = xp[c][q * 8];
        #pragma unroll
        for (int j = 1; j < 8; ++j) m = fmaxf(m, xp[c][q * 8 + j]);
        partial = m * fcw[tid];
    }
    __syncthreads();
    float* red = &ssm[0][0];
    if (tid < 128) red[tid] = partial;
    __syncthreads();
    if (tid < 64) {
        float v = red[tid] + red[tid + 64];
        #pragma unroll
        for (int off = 32; off > 0; off >>= 1) v += __shfl_down(v, off, 64);
        if (tid == 0) out[g] = v + fcb[0];
    }
}

extern "C" void kernel_launch(void* const* d_in, const int* in_sizes, int n_in,
                              void* d_out, int out_size, void* d_ws, size_t ws_size,
                              hipStream_t stream) {
    const float* x      = (const float*)d_in[0];
    const int*   ei     = (const int*)d_in[1];
    // d_in[2] = adj: dead code in the reference
    const float* s      = (const float*)d_in[3];
    const float* Wroot1 = (const float*)d_in[4];
    const float* Wrel1  = (const float*)d_in[5];
    const float* b1     = (const float*)d_in[6];
    const float* Wroot2 = (const float*)d_in[7];
    const float* Wrel2  = (const float*)d_in[8];
    const float* b2     = (const float*)d_in[9];
    const float* Wroot3 = (const float*)d_in[10];
    const float* Wrel3  = (const float*)d_in[11];
    const float* b3     = (const float*)d_in[12];
    const float* fcw    = (const float*)d_in[13];
    const float* fcb    = (const float*)d_in[14];
    float* out = (float*)d_out;
    unsigned short* wpack = (unsigned short*)d_ws;   // 65536 bf16 = 128 KB

    const int nE = in_sizes[1] / 2;
    const int B  = in_sizes[3] / (NPER * NC);

    pack_w<<<256, 256, 0, stream>>>(Wrel2, Wroot2, Wrel3, Wroot3, wpack);
    gnn_kernel<<<B, 256, 0, stream>>>(x, ei, s,
                                      Wroot1, Wrel1, b1,
                                      b2, b3, wpack,
                                      fcw, fcb, out, nE);
}

// Round 3
// 186.760 us; speedup vs baseline: 2.8661x; 1.1122x over previous
//
#include <hip/hip_runtime.h>
#include <hip/hip_bf16.h>

#define NPER 68
#define ROWP 80
#define EPER 544
#define FH   128
#define NC   8
#define ADJW 104   // adj/sT row stride in elements (2-way-conflict-free, fits k<=95)

typedef short short8 __attribute__((ext_vector_type(8)));
typedef float f32x4 __attribute__((ext_vector_type(4)));

__device__ __forceinline__ unsigned short f2bf(float f) {
    unsigned int u = __float_as_uint(f);
    return (unsigned short)((u + 0x7FFFu + ((u >> 16) & 1u)) >> 16);
}
__device__ __forceinline__ float bf2f(unsigned short h) {
    return __uint_as_float(((unsigned int)h) << 16);
}
// hcat swizzle: row stride 512B; XOR 16B-unit index (bits 4..6) with (row^(row>>3))&7.
// Conflict analysis: A-frag reads (16 rows, same 16B col) <=2-way; B-gathers
// (4 row-groups stride 8, 32B window) 2-way; epilogue scalar writes ~free.
__device__ __forceinline__ unsigned int swzB(unsigned int row, unsigned int bc) {
    return row * 512u + (bc ^ (((row ^ (row >> 3)) & 7u) << 4));
}

// Pack [Wrel;Wroot] (256x128 f32) into MFMA-B-fragment-ordered bf16 (layers 2,3):
// ws[(((L*8+t)*8+n)*64+l)*8+j] = Wcat[t*32+(l>>4)*8+j][n*16+(l&15)]
__global__ void pack_w(const float* __restrict__ Wrel2, const float* __restrict__ Wroot2,
                       const float* __restrict__ Wrel3, const float* __restrict__ Wroot3,
                       unsigned short* __restrict__ ws) {
    int o = blockIdx.x * 256 + threadIdx.x;      // < 65536
    int j = o & 7, l = (o >> 3) & 63, n = (o >> 9) & 7, t = (o >> 12) & 7, L = o >> 15;
    int k = t * 32 + ((l >> 4) << 3) + j;
    int f = n * 16 + (l & 15);
    const float* Wl = L ? Wrel3 : Wrel2;
    const float* Wr = L ? Wroot3 : Wroot2;
    float v = (k < FH) ? Wl[k * FH + f] : Wr[(k - FH) * FH + f];
    ws[o] = f2bf(v);
}

// One block per graph, 256 threads = 4 waves. LDS ~66.6KB -> 2 blocks/CU.
__launch_bounds__(256, 2)
__global__ void gnn_kernel(const float* __restrict__ x,
                           const int*   __restrict__ ei,
                           const float* __restrict__ s,
                           const float* __restrict__ Wroot1, const float* __restrict__ Wrel1,
                           const float* __restrict__ b1,
                           const float* __restrict__ b2, const float* __restrict__ b3,
                           const unsigned short* __restrict__ wpack,
                           const float* __restrict__ fcw, const float* __restrict__ fcb,
                           float* __restrict__ out, int nE)
{
    // hcat[row][k]: k 0..127 = agg part, 128..255 = h part. bf16, swizzled.
    __shared__ __align__(16) unsigned short hcat[ROWP * 256];   // 40960 B
    __shared__ __align__(16) unsigned short adjb[ROWP * ADJW];  // 16640 B (u16 counts -> bf16)
    __shared__ __align__(16) unsigned short sT[16 * ADJW];      // 3328 B  (softmax(s)^T bf16)
    __shared__ float xl[NPER][2];                               // 544 B
    __shared__ float xp[NC][FH];                                // 4096 B
    __shared__ float red[128];                                  // 512 B

    const int g = blockIdx.x, tid = threadIdx.x, lane = tid & 63, wid = tid >> 6;
    const int gnode = g * NPER, gedge = g * EPER;
    const int* srcp = ei;
    const int* dstp = ei + nE;
    unsigned int* adj32 = (unsigned int*)adjb;
    unsigned int* h32   = (unsigned int*)hcat;

    // ---- zero init ----
    for (int i = tid; i < (ROWP * ADJW) / 2; i += 256) adj32[i] = 0u;
    for (int i = tid; i < (16 * ADJW) / 2; i += 256) ((unsigned int*)sT)[i] = 0u;
    for (int i = tid; i < 12 * 128; i += 256) h32[NPER * 128 + i] = 0u;          // rows 68..79
    for (int i = tid; i < NPER * 32; i += 256) h32[(i >> 5) * 128 + (i & 31)] = 0u; // rows<68, agg cols 0..63
    for (int i = tid; i < NPER * 2; i += 256) ((float*)xl)[i] = x[gnode * 2 + i];
    __syncthreads();

    // ---- edges -> adjacency counts (u16 halves of u32, atomic) ----
    for (int e = tid; e < EPER; e += 256) {
        int s_ = srcp[gedge + e] - gnode;
        int d_ = dstp[gedge + e] - gnode;
        int idx = d_ * ADJW + s_;
        atomicAdd(&adj32[idx >> 1], (idx & 1) ? 0x10000u : 1u);
    }
    __syncthreads();
    // in-place convert u16 counts -> bf16
    for (int i = tid; i < (ROWP * ADJW) / 2; i += 256) {
        unsigned int u = adj32[i];
        if (u) {
            adj32[i] = (unsigned int)f2bf((float)(u & 0xffffu))
                     | ((unsigned int)f2bf((float)(u >> 16)) << 16);
        }
    }
    __syncthreads();

    // ---- layer-1 A prep (agg of x via Adj) + softmax(s)^T ----
    if (tid < 136) {
        int i = tid >> 1, ft = tid & 1;
        float a = 0.f;
        for (int j = 0; j < NPER; ++j) a += bf2f(adjb[i * ADJW + j]) * xl[j][ft];
        *(unsigned short*)((char*)hcat + swzB(i, ft * 2))     = f2bf(a);
        *(unsigned short*)((char*)hcat + swzB(i, 4 + ft * 2)) = f2bf(xl[i][ft]);
    } else if (tid < 204) {
        int i = tid - 136;
        float v[NC]; float m = -1e30f;
        #pragma unroll
        for (int c = 0; c < NC; ++c) { v[c] = s[(gnode + i) * NC + c]; m = fmaxf(m, v[c]); }
        float sum = 0.f;
        #pragma unroll
        for (int c = 0; c < NC; ++c) { v[c] = __expf(v[c] - m); sum += v[c]; }
        float inv = 1.f / sum;
        #pragma unroll
        for (int c = 0; c < NC; ++c) sT[c * ADJW + i] = f2bf(v[c] * inv);
    }
    __syncthreads();

    const int arow = lane & 15, aq = lane >> 4, akB = aq * 16;

    // epilogue: acc + bias -> relu -> h part (rows < 68)
    auto epilogue_h = [&](f32x4 (&acc)[5][2], const float* __restrict__ bv) {
        #pragma unroll
        for (int c2 = 0; c2 < 2; ++c2) {
            int f = (wid * 2 + c2) * 16 + arow;
            float bias = bv[f];
            #pragma unroll
            for (int m = 0; m < 5; ++m)
                #pragma unroll
                for (int i2 = 0; i2 < 4; ++i2) {
                    int row = m * 16 + aq * 4 + i2;
                    if (row < NPER) {
                        float v = acc[m][c2][i2] + bias;
                        v = v > 0.f ? v : 0.f;
                        *(unsigned short*)((char*)hcat + swzB(row, (FH + f) * 2)) = f2bf(v);
                    }
                }
        }
    };

    // ---- layer 1: h = relu([aggx|x] @ Wcat1 + b1), K=32 MFMA ----
    {
        f32x4 acc[5][2];
        #pragma unroll
        for (int m = 0; m < 5; ++m) { acc[m][0] = (f32x4)0.f; acc[m][1] = (f32x4)0.f; }
        short8 bf[2];
        #pragma unroll
        for (int c2 = 0; c2 < 2; ++c2) {
            int f = (wid * 2 + c2) * 16 + arow;
            #pragma unroll
            for (int j = 0; j < 8; ++j) {
                float wv = 0.f;
                if (aq == 0) {              // k = j, only k<4 nonzero
                    if (j < 2) wv = Wrel1[j * FH + f];
                    else if (j < 4) wv = Wroot1[(j - 2) * FH + f];
                }
                bf[c2][j] = (short)f2bf(wv);
            }
        }
        #pragma unroll
        for (int m = 0; m < 5; ++m) {
            short8 a = *(const short8*)((char*)hcat + swzB(m * 16 + arow, akB));
            acc[m][0] = __builtin_amdgcn_mfma_f32_16x16x32_bf16(a, bf[0], acc[m][0], 0, 0, 0);
            acc[m][1] = __builtin_amdgcn_mfma_f32_16x16x32_bf16(a, bf[1], acc[m][1], 0, 0, 0);
        }
        epilogue_h(acc, b1);   // writes h part only; L1 A-reads were agg-part only
    }
    __syncthreads();

    // ---- layers 2,3: agg = Adj@h (MFMA), then h' = relu([agg|h]@Wcat+b) ----
    #pragma unroll 1
    for (int L = 0; L < 2; ++L) {
        // agg GEMM: A=Adj[80x96], B=h gathered column-wise
        f32x4 acc[5][2];
        #pragma unroll
        for (int m = 0; m < 5; ++m) { acc[m][0] = (f32x4)0.f; acc[m][1] = (f32x4)0.f; }
        for (int kt = 0; kt < 3; ++kt) {
            short8 bg[2];
            #pragma unroll
            for (int c2 = 0; c2 < 2; ++c2) {
                int f = (wid * 2 + c2) * 16 + arow;
                unsigned int cb = (FH + f) * 2;
                #pragma unroll
                for (int j = 0; j < 8; ++j) {
                    int k = kt * 32 + aq * 8 + j;
                    int r = k < ROWP ? k : 0;   // k>=80: Adj cols are 0 -> product 0
                    bg[c2][j] = (short)*(const unsigned short*)((char*)hcat + swzB(r, cb));
                }
            }
            #pragma unroll
            for (int m = 0; m < 5; ++m) {
                short8 a = *(const short8*)((char*)adjb + (m * 16 + arow) * (ADJW * 2) + kt * 64 + akB);
                acc[m][0] = __builtin_amdgcn_mfma_f32_16x16x32_bf16(a, bg[0], acc[m][0], 0, 0, 0);
                acc[m][1] = __builtin_amdgcn_mfma_f32_16x16x32_bf16(a, bg[1], acc[m][1], 0, 0, 0);
            }
        }
        // agg epilogue -> agg part (no bias/relu), rows < 68
        #pragma unroll
        for (int c2 = 0; c2 < 2; ++c2) {
            int f = (wid * 2 + c2) * 16 + arow;
            #pragma unroll
            for (int m = 0; m < 5; ++m)
                #pragma unroll
                for (int i2 = 0; i2 < 4; ++i2) {
                    int row = m * 16 + aq * 4 + i2;
                    if (row < NPER)
                        *(unsigned short*)((char*)hcat + swzB(row, f * 2)) = f2bf(acc[m][c2][i2]);
                }
        }
        __syncthreads();

        // main GEMM: [agg|h] @ Wcat, K=256
        f32x4 acc2[5][2];
        #pragma unroll
        for (int m = 0; m < 5; ++m) { acc2[m][0] = (f32x4)0.f; acc2[m][1] = (f32x4)0.f; }
        const unsigned short* wsL = wpack + (L << 15);
        for (int t = 0; t < 8; ++t) {
            short8 bf0 = *(const short8*)(wsL + (((t * 8 + wid * 2 + 0) * 64 + lane) << 3));
            short8 bf1 = *(const short8*)(wsL + (((t * 8 + wid * 2 + 1) * 64 + lane) << 3));
            #pragma unroll
            for (int m = 0; m < 5; ++m) {
                short8 a = *(const short8*)((char*)hcat + swzB(m * 16 + arow, t * 64 + akB));
                acc2[m][0] = __builtin_amdgcn_mfma_f32_16x16x32_bf16(a, bf0, acc2[m][0], 0, 0, 0);
                acc2[m][1] = __builtin_amdgcn_mfma_f32_16x16x32_bf16(a, bf1, acc2[m][1], 0, 0, 0);
            }
        }
        __syncthreads();                 // all A reads done before h overwrite
        epilogue_h(acc2, L ? b3 : b2);
        __syncthreads();
    }

    // ---- diff-pool: xp = sT @ h via MFMA (M=16, rows 8..15 zero) ----
    {
        f32x4 accp[2]; accp[0] = (f32x4)0.f; accp[1] = (f32x4)0.f;
        for (int kt = 0; kt < 3; ++kt) {
            short8 bg[2];
            #pragma unroll
            for (int c2 = 0; c2 < 2; ++c2) {
                int f = (wid * 2 + c2) * 16 + arow;
                unsigned int cb = (FH + f) * 2;
                #pragma unroll
                for (int j = 0; j < 8; ++j) {
                    int k = kt * 32 + aq * 8 + j;
                    int r = k < ROWP ? k : 0;   // k>=80: sT cols are 0
                    bg[c2][j] = (short)*(const unsigned short*)((char*)hcat + swzB(r, cb));
                }
            }
            short8 a = *(const short8*)(sT + arow * ADJW + kt * 32 + aq * 8);
            accp[0] = __builtin_amdgcn_mfma_f32_16x16x32_bf16(a, bg[0], accp[0], 0, 0, 0);
            accp[1] = __builtin_amdgcn_mfma_f32_16x16x32_bf16(a, bg[1], accp[1], 0, 0, 0);
        }
        #pragma unroll
        for (int c2 = 0; c2 < 2; ++c2) {
            int f = (wid * 2 + c2) * 16 + arow;
            if (aq < 2) {
                #pragma unroll
                for (int i2 = 0; i2 < 4; ++i2) xp[aq * 4 + i2][f] = accp[c2][i2];
            }
        }
    }
    __syncthreads();

    // ---- maxpool (1,8) + FC ----
    float partial = 0.f;
    if (tid < 128) {
        int c = tid >> 4, q = tid & 15;
        float m = xp[c][q * 8];
        #pragma unroll
        for (int j = 1; j < 8; ++j) m = fmaxf(m, xp[c][q * 8 + j]);
        partial = m * fcw[tid];
    }
    if (tid < 128) red[tid] = partial;
    __syncthreads();
    if (tid < 64) {
        float v = red[tid] + red[tid + 64];
        #pragma unroll
        for (int off = 32; off > 0; off >>= 1) v += __shfl_down(v, off, 64);
        if (tid == 0) out[g] = v + fcb[0];
    }
}

extern "C" void kernel_launch(void* const* d_in, const int* in_sizes, int n_in,
                              void* d_out, int out_size, void* d_ws, size_t ws_size,
                              hipStream_t stream) {
    const float* x      = (const float*)d_in[0];
    const int*   ei     = (const int*)d_in[1];
    // d_in[2] = adj: dead code in the reference
    const float* s      = (const float*)d_in[3];
    const float* Wroot1 = (const float*)d_in[4];
    const float* Wrel1  = (const float*)d_in[5];
    const float* b1     = (const float*)d_in[6];
    const float* Wroot2 = (const float*)d_in[7];
    const float* Wrel2  = (const float*)d_in[8];
    const float* b2     = (const float*)d_in[9];
    const float* Wroot3 = (const float*)d_in[10];
    const float* Wrel3  = (const float*)d_in[11];
    const float* b3     = (const float*)d_in[12];
    const float* fcw    = (const float*)d_in[13];
    const float* fcb    = (const float*)d_in[14];
    float* out = (float*)d_out;
    unsigned short* wpack = (unsigned short*)d_ws;   // 65536 bf16 = 128 KB

    const int nE = in_sizes[1] / 2;
    const int B  = in_sizes[3] / (NPER * NC);

    pack_w<<<256, 256, 0, stream>>>(Wrel2, Wroot2, Wrel3, Wroot3, wpack);
    gnn_kernel<<<B, 256, 0, stream>>>(x, ei, s,
                                      Wroot1, Wrel1, b1,
                                      b2, b3, wpack,
                                      fcw, fcb, out, nE);
}